// Round 7
// baseline (282.213 us; speedup 1.0000x reference)
//
#include <hip/hip_runtime.h>

#define TT   512
#define HH   50
#define MB   8            // batch rows per block
#define NW   13           // waves per block
#define NTHR (NW * 64)    // 832 threads

typedef _Float16 f16x8 __attribute__((ext_vector_type(8)));
typedef float    f32x4 __attribute__((ext_vector_type(4)));

#define L2E 1.4426950408889634f

__device__ __forceinline__ float rcp_f(float v) { return __builtin_amdgcn_rcpf(v); }
__device__ __forceinline__ float ex2_f(float v) { return __builtin_amdgcn_exp2f(v); }

// 13 waves, grid 256. Wave w owns gate-tile w (units 4w..4w+3, A-rows interleaved
// i,f,g,o). Lane (q=l>>4, n=l&15): acc[e] = gate e of unit u=4w+q, col n.
// h0 at cols 0-7 (+copy at 8-15); h1 at cols 8-15. Lanes n<8 run L0, n>=8 run L1.
// K-slot trick: B-row 50 = x_t (relayed per step), row 51 = 1.0 (constant);
// A carries scaled W_ih0 / summed-bias there -> gate = acc directly (no adds/FMAs).
// Weights pre-scaled by -log2e (i,f,o) / +2log2e (g) so exp2 args are direct.
// One barrier per step; layer 1 pipelined one step behind layer 0.
__global__ __launch_bounds__(NTHR, 1)
void lstm2_kernel(const float* __restrict__ x,
                  const float* __restrict__ W_ih0, const float* __restrict__ W_hh0,
                  const float* __restrict__ b_ih0, const float* __restrict__ b_hh0,
                  const float* __restrict__ W_ih1, const float* __restrict__ W_hh1,
                  const float* __restrict__ b_ih1, const float* __restrict__ b_hh1,
                  const float* __restrict__ W_fc,  const float* __restrict__ b_fc,
                  float* __restrict__ out)
{
    // h layout [parity][ki][q][col][e] f16; row k -> (ki=k>>5, q=(k>>3)&3, e=k&7).
    // Lane (q,n) B-frag read at [P][ki][q][n][0..7]: 16B, lane-linear.
    __shared__ __align__(16) _Float16 sh0[2][2][4][16][8];   // 4 KiB
    __shared__ __align__(16) _Float16 sh1[2][2][4][16][8];   // 4 KiB
    __shared__ _Float16 sh_xh[MB][TT + 8];                   // x as f16, +pad (zeroed)
    __shared__ float shf[MB][52];
    __shared__ float sh_wfc[HH];

    const int tid = threadIdx.x;
    const int w   = tid >> 6;
    const int l   = tid & 63;
    const int q   = l >> 4;
    const int n   = l & 15;
    const int b0  = blockIdx.x * MB;

    for (int i = tid; i < 2 * 2 * 4 * 16 * 8; i += NTHR) {
        (&sh0[0][0][0][0][0])[i] = (_Float16)0.0f;
        (&sh1[0][0][0][0][0])[i] = (_Float16)0.0f;
    }
    for (int i = tid; i < MB * TT; i += NTHR)
        sh_xh[i >> 9][i & (TT - 1)] = (_Float16)x[(size_t)b0 * TT + i];
    for (int i = tid; i < MB * 8; i += NTHR)
        sh_xh[i >> 3][TT + (i & 7)] = (_Float16)0.0f;    // pad: xt=512 reads 0
    for (int i = tid; i < HH; i += NTHR) sh_wfc[i] = W_fc[i];
    __syncthreads();
    // constant bias-carrier row 51 (ki=1,q=2,e=3), both parities, all cols;
    // x_0 into buf 0 row 50 (ki=1,q=2,e=2), cols 0-7.
    if (tid < 32) sh0[tid >> 4][1][2][tid & 15][3] = (_Float16)1.0f;
    if (tid < MB) sh0[0][1][2][tid][2] = (_Float16)x[(size_t)(b0 + tid) * TT];

    // ---- A fragments (weights), gate-scaled, with affine K-slots. A-row r=n ->
    // unit 4w+(n>>2), gate n&3, weight row grow = (n&3)*HH + u_r.
    // k-map: k = ki*32 + q*8 + e (same bijection as B layout -> sums correct).
    const int  u_r   = w * 4 + (n >> 2);
    const bool rowok = (u_r < HH);
    const int  grow  = (n & 3) * HH + (rowok ? u_r : 0);
    const float srow = ((n & 3) == 2) ? (2.0f * L2E) : (-L2E);

    f16x8 whh0[2], wih1[2], whh1[2];
    #pragma unroll
    for (int ki = 0; ki < 2; ++ki) {
        #pragma unroll
        for (int e = 0; e < 8; ++e) {
            int k = ki * 32 + q * 8 + e;
            float a0v = 0.0f, a1v = 0.0f, a2v = 0.0f;
            if (rowok) {
                if (k < HH) {
                    a0v = W_hh0[grow * HH + k];
                    a1v = W_ih1[grow * HH + k];
                    a2v = W_hh1[grow * HH + k];
                } else if (k == HH) {          // x slot (layer 0 input weight)
                    a0v = W_ih0[grow];
                } else if (k == HH + 1) {      // bias slot
                    a0v = b_ih0[grow] + b_hh0[grow];
                    a1v = b_ih1[grow] + b_hh1[grow];
                }
            }
            whh0[ki][e] = (_Float16)(srow * a0v);
            wih1[ki][e] = (_Float16)(srow * a1v);
            whh1[ki][e] = (_Float16)(srow * a2v);
        }
    }

    // ---- chain identity: lane n<8 = L0 batch n; lane n>=8 = L1 batch n-8 ----
    const bool isL1 = (n >= 8);
    const int  u    = 4 * w + q;
    const int  cb   = n & 7;
    const bool wr   = (u < HH);
    const int  uc   = wr ? u : 0;

    // x-relay lanes: wave 12's junk q=2 group, lanes n<8 (their chains are pad units)
    const bool wrel = (w == 12) && (q == 2) && (n < 8);

    // write ptrs: L0 -> sh0[buf][..][cb] (+copy at col cb+8 = +64 f16);
    //             L1 -> sh1[buf][..][cb+8]. Step P writes buf P^1.
    const int uk = uc >> 5, uq2 = (uc >> 3) & 3, ue = uc & 7;
    _Float16* wpA0 = isL1 ? &sh1[1][uk][uq2][cb + 8][ue] : &sh0[1][uk][uq2][cb][ue];
    _Float16* wpA1 = isL1 ? &sh1[0][uk][uq2][cb + 8][ue] : &sh0[0][uk][uq2][cb][ue];

    const f32x4 z = {0.0f, 0.0f, 0.0f, 0.0f};
    float cst = 0.0f;
    int   xt  = 1;

    __syncthreads();

#define MFMA(A, B, C) __builtin_amdgcn_mfma_f32_16x16x32_f16((A), (B), (C), 0, 0, 0)

#define STEP(P, T0)                                                               \
    {                                                                             \
        f16x8 hb0 = *(const f16x8*)&sh0[P][0][q][n][0];                           \
        f16x8 hb1 = *(const f16x8*)&sh0[P][1][q][n][0];                           \
        f16x8 pb0 = *(const f16x8*)&sh1[P][0][q][n][0];                           \
        f16x8 pb1 = *(const f16x8*)&sh1[P][1][q][n][0];                           \
        f32x4 a0 = MFMA(whh0[0], hb0, z);                                         \
        a0 = MFMA(whh0[1], hb1, a0);                                              \
        f32x4 a1 = MFMA(wih1[0], hb0, z);                                         \
        a1 = MFMA(wih1[1], hb1, a1);                                              \
        f32x4 a2 = MFMA(whh1[0], pb0, z);                                         \
        a2 = MFMA(whh1[1], pb1, a2);                                              \
        a1 += a2;                                                                 \
        if (wrel) sh0[(P) ^ 1][1][2][n][2] = sh_xh[n][xt];                        \
        ++xt;                                                                     \
        float g0 = isL1 ? a1[0] : a0[0];                                          \
        float g1 = isL1 ? a1[1] : a0[1];                                          \
        float g2 = isL1 ? a1[2] : a0[2];                                          \
        float g3 = isL1 ? a1[3] : a0[3];                                          \
        float eI = ex2_f(g0), eF = ex2_f(g1), tG = ex2_f(g2), eO = ex2_f(g3);     \
        float dI = 1.0f + eI, dF = 1.0f + eF, dO = 1.0f + eO;                     \
        float IG = (tG - 1.0f) * rcp_f(dI * (tG + 1.0f));                         \
        float cn = __builtin_fmaf(rcp_f(dF), cst, IG);                            \
        cst = ((T0) && isL1) ? 0.0f : cn;                                         \
        float cc = fminf(fmaxf(cst, -16.0f), 16.0f);                              \
        float tc = ex2_f(cc * (2.0f * L2E));                                      \
        float hv = (tc - 1.0f) * rcp_f(dO * (tc + 1.0f));                         \
        if (wr && !((T0) && isL1)) {                                              \
            _Float16 h16 = (_Float16)hv;                                          \
            _Float16* wp = (P) ? wpA1 : wpA0;                                     \
            wp[0] = h16;                                                          \
            if (!isL1) wp[64] = h16;   /* h0 copy at col cb+8 */                  \
        }                                                                         \
        __syncthreads();                                                          \
    }

    // t=0 (P=0): L1 chain suppressed (h1(-1) stays 0)
    STEP(0, 1)
    // t=1..510: 255 (odd,even) pairs
    for (int k2 = 0; k2 < 255; ++k2) {
        STEP(1, 0)
        STEP(0, 0)
    }
    // t=511 (P=1): writes h0(511), h1(510) into buf 0; xt=512 reads zero pad
    STEP(1, 0)
#undef STEP

    // ---- tail: h1(511) from h0(511), h1(510) (both in buf 0) ----
    {
        f16x8 hb0 = *(const f16x8*)&sh0[0][0][q][n][0];
        f16x8 hb1 = *(const f16x8*)&sh0[0][1][q][n][0];
        f16x8 pb0 = *(const f16x8*)&sh1[0][0][q][n][0];
        f16x8 pb1 = *(const f16x8*)&sh1[0][1][q][n][0];
        f32x4 a1 = MFMA(wih1[0], hb0, z);
        a1 = MFMA(wih1[1], hb1, a1);
        a1 = MFMA(whh1[0], pb0, a1);
        a1 = MFMA(whh1[1], pb1, a1);
        if (isL1 && wr) {
            float eI = ex2_f(a1[0]), eF = ex2_f(a1[1]);
            float tG = ex2_f(a1[2]), eO = ex2_f(a1[3]);
            float dI = 1.0f + eI, dF = 1.0f + eF, dO = 1.0f + eO;
            float IG = (tG - 1.0f) * rcp_f(dI * (tG + 1.0f));
            float cn = __builtin_fmaf(rcp_f(dF), cst, IG);
            float cc = fminf(fmaxf(cn, -16.0f), 16.0f);
            float tc = ex2_f(cc * (2.0f * L2E));
            shf[cb][uc] = (tc - 1.0f) * rcp_f(dO * (tc + 1.0f));
        }
    }
    __syncthreads();

    if (tid < MB) {
        float s = b_fc[0];
        for (int j = 0; j < HH; ++j) s += shf[tid][j] * sh_wfc[j];
        out[b0 + tid] = s;
    }
#undef MFMA
}

extern "C" void kernel_launch(void* const* d_in, const int* in_sizes, int n_in,
                              void* d_out, int out_size, void* d_ws, size_t ws_size,
                              hipStream_t stream) {
    const float* xin   = (const float*)d_in[0];
    const float* W_ih0 = (const float*)d_in[1];
    const float* W_hh0 = (const float*)d_in[2];
    const float* b_ih0 = (const float*)d_in[3];
    const float* b_hh0 = (const float*)d_in[4];
    const float* W_ih1 = (const float*)d_in[5];
    const float* W_hh1 = (const float*)d_in[6];
    const float* b_ih1 = (const float*)d_in[7];
    const float* b_hh1 = (const float*)d_in[8];
    const float* W_fc  = (const float*)d_in[9];
    const float* b_fc  = (const float*)d_in[10];
    float* out = (float*)d_out;

    lstm2_kernel<<<dim3(2048 / MB), dim3(NTHR), 0, stream>>>(
        xin, W_ih0, W_hh0, b_ih0, b_hh0, W_ih1, W_hh1, b_ih1, b_hh1, W_fc, b_fc, out);
}